// Round 1
// baseline (311.073 us; speedup 1.0000x reference)
//
#include <hip/hip_runtime.h>
#include <cstdint>
#include <cstddef>

typedef unsigned short u16;
typedef __bf16 bf16x8 __attribute__((ext_vector_type(8)));
typedef float f32x4 __attribute__((ext_vector_type(4)));

// fp32 -> bf16 round-to-nearest-even (inputs finite)
__device__ inline u16 f2b(float f) {
    uint32_t u = __builtin_bit_cast(uint32_t, f);
    u += 0x7FFFu + ((u >> 16) & 1u);
    return (u16)(u >> 16);
}

// ---------------- prep: fp32 -> bf16 convert (x) ----------------
__global__ void convert_x_kernel(const float* __restrict__ x, u16* __restrict__ xb) {
    size_t i = ((size_t)blockIdx.x * 256 + threadIdx.x) * 4;
    float4 v = *(const float4*)(x + i);
    uint2 pack;
    pack.x = (uint32_t)f2b(v.x) | ((uint32_t)f2b(v.y) << 16);
    pack.y = (uint32_t)f2b(v.z) | ((uint32_t)f2b(v.w) << 16);
    *(uint2*)(xb + i) = pack;
}

// ---------------- prep: W [k][n] fp32 -> WT [n][k] bf16 ----------------
__global__ void transpose_w_kernel(const float* __restrict__ W, u16* __restrict__ WT) {
    __shared__ u16 t[32][33];
    const int bx = blockIdx.x * 32;  // n origin
    const int by = blockIdx.y * 32;  // k origin
    const int tx = threadIdx.x, ty = threadIdx.y;
    #pragma unroll
    for (int r = 0; r < 32; r += 8)
        t[ty + r][tx] = f2b(W[(size_t)(by + ty + r) * 1024 + bx + tx]);
    __syncthreads();
    #pragma unroll
    for (int r = 0; r < 32; r += 8)
        WT[(size_t)(bx + ty + r) * 1024 + (by + tx)] = t[tx][ty + r];
}

// ---------------- generic NT GEMM: C = A (MxK) * B^T, B stored [N][K] ----------------
// EPI 0: C bf16 = acc*scale           (projections; V path writes V^T naturally)
// EPI 2: causal mask + exp -> P bf16, atomicAdd row sums into lbuf
// EPI 3: C fp32 = acc / lbuf[row]     (output), K limited to (it+1)*128
template<int EPI>
__global__ __launch_bounds__(256)
void gemm_nt(const u16* __restrict__ A, int lda, long long sAz,
             const u16* __restrict__ B, int ldb, long long sBz,
             void* __restrict__ Cv, int ldc, long long sCzBytes,
             int K, float scale, float* __restrict__ lbuf) {
    constexpr int BM = 128, BN = 128, BK = 32;
    __shared__ __align__(16) u16 Asm[BM * BK];
    __shared__ __align__(16) u16 Bsm[BN * BK];

    const int jt = blockIdx.x, it = blockIdx.y, z = blockIdx.z;
    if (EPI == 2) { if (jt > it) return; }  // causal tile skip

    A += (size_t)z * sAz;
    B += (size_t)z * sBz;
    char* Cb = (char*)Cv + (size_t)z * sCzBytes;
    if (EPI == 2 || EPI == 3) lbuf += (size_t)z * 2048;

    const int m0 = it * BM, n0 = jt * BN;
    const int Kloc = (EPI == 3) ? (it + 1) * 128 : K;

    const int tid = threadIdx.x;
    const int lane = tid & 63, wave = tid >> 6;
    const int wm = wave >> 1, wn = wave & 1;       // 2x2 wave grid, 64x64 per wave
    const int srow = tid >> 2, skoff = (tid & 3) * 8;
    const int fl = lane & 15, fh = lane >> 4;

    const f32x4 vzero = {0.f, 0.f, 0.f, 0.f};
    f32x4 acc[4][4];
    #pragma unroll
    for (int i = 0; i < 4; ++i)
        #pragma unroll
        for (int j = 0; j < 4; ++j) acc[i][j] = vzero;

    const u16* Ap = A + (size_t)(m0 + srow) * lda + skoff;
    const u16* Bp = B + (size_t)(n0 + srow) * ldb + skoff;

    for (int k0 = 0; k0 < Kloc; k0 += BK) {
        uint4 a0 = *(const uint4*)(Ap + k0);
        uint4 a1 = *(const uint4*)(Ap + k0 + (size_t)64 * lda);
        uint4 b0 = *(const uint4*)(Bp + k0);
        uint4 b1 = *(const uint4*)(Bp + k0 + (size_t)64 * ldb);
        __syncthreads();
        *(uint4*)&Asm[srow * BK + skoff]        = a0;
        *(uint4*)&Asm[(srow + 64) * BK + skoff] = a1;
        *(uint4*)&Bsm[srow * BK + skoff]        = b0;
        *(uint4*)&Bsm[(srow + 64) * BK + skoff] = b1;
        __syncthreads();
        bf16x8 af[4], bfr[4];
        #pragma unroll
        for (int t = 0; t < 4; ++t) {
            af[t]  = *(const bf16x8*)&Asm[(wm * 64 + t * 16 + fl) * BK + fh * 8];
            bfr[t] = *(const bf16x8*)&Bsm[(wn * 64 + t * 16 + fl) * BK + fh * 8];
        }
        #pragma unroll
        for (int mt = 0; mt < 4; ++mt)
            #pragma unroll
            for (int nt = 0; nt < 4; ++nt)
                acc[mt][nt] = __builtin_amdgcn_mfma_f32_16x16x32_bf16(
                    af[mt], bfr[nt], acc[mt][nt], 0, 0, 0);
    }

    if (EPI == 0) {
        u16* Cp = (u16*)Cb;
        #pragma unroll
        for (int mt = 0; mt < 4; ++mt)
            #pragma unroll
            for (int nt = 0; nt < 4; ++nt)
                #pragma unroll
                for (int r = 0; r < 4; ++r) {
                    int row = m0 + wm * 64 + mt * 16 + fh * 4 + r;
                    int col = n0 + wn * 64 + nt * 16 + fl;
                    Cp[(size_t)row * ldc + col] = f2b(acc[mt][nt][r] * scale);
                }
    } else if (EPI == 2) {
        u16* Cp = (u16*)Cb;
        #pragma unroll
        for (int mt = 0; mt < 4; ++mt)
            #pragma unroll
            for (int r = 0; r < 4; ++r) {
                int row = m0 + wm * 64 + mt * 16 + fh * 4 + r;
                float part = 0.f;
                #pragma unroll
                for (int nt = 0; nt < 4; ++nt) {
                    int col = n0 + wn * 64 + nt * 16 + fl;
                    float p = (col <= row) ? __expf(acc[mt][nt][r]) : 0.f;
                    part += p;
                    Cp[(size_t)row * ldc + col] = f2b(p);
                }
                #pragma unroll
                for (int off = 1; off < 16; off <<= 1)
                    part += __shfl_xor(part, off, 64);
                if (fl == 0) atomicAdd(lbuf + row, part);
            }
    } else {
        float* Cp = (float*)Cb;
        #pragma unroll
        for (int mt = 0; mt < 4; ++mt)
            #pragma unroll
            for (int r = 0; r < 4; ++r) {
                int row = m0 + wm * 64 + mt * 16 + fh * 4 + r;
                float inv = 1.0f / lbuf[row];
                #pragma unroll
                for (int nt = 0; nt < 4; ++nt) {
                    int col = n0 + wn * 64 + nt * 16 + fl;
                    Cp[(size_t)row * ldc + col] = acc[mt][nt][r] * inv;
                }
            }
    }
}

extern "C" void kernel_launch(void* const* d_in, const int* in_sizes, int n_in,
                              void* d_out, int out_size, void* d_ws, size_t ws_size,
                              hipStream_t stream) {
    (void)in_sizes; (void)n_in; (void)out_size; (void)ws_size;
    const float* x  = (const float*)d_in[0];
    const float* Wq = (const float*)d_in[1];
    const float* Wk = (const float*)d_in[2];
    const float* Wv = (const float*)d_in[3];
    float* out = (float*)d_out;

    const size_t MB = 1u << 20;
    char* ws = (char*)d_ws;
    u16* xb  = (u16*)(ws);              // [8192][1024] bf16   16 MB
    u16* WqT = (u16*)(ws + 16 * MB);    // [1024][1024] bf16    2 MB
    u16* WkT = (u16*)(ws + 18 * MB);
    u16* WvT = (u16*)(ws + 20 * MB);
    u16* Qs  = (u16*)(ws + 22 * MB);    // scaled Q bf16       16 MB
    u16* Kb  = (u16*)(ws + 38 * MB);    // K bf16              16 MB
    u16* Vt  = (u16*)(ws + 54 * MB);    // V^T [1024][8192]    16 MB
    u16* P   = (u16*)(ws + 70 * MB);    // exp(S) [4][2048][2048] 32 MB
    float* l = (float*)(ws + 102 * MB); // row sums [4][2048]  32 KB

    // prep
    hipMemsetAsync(l, 0, 8192 * sizeof(float), stream);
    convert_x_kernel<<<8192, 256, 0, stream>>>(x, xb);
    transpose_w_kernel<<<dim3(32, 32), dim3(32, 8), 0, stream>>>(Wq, WqT);
    transpose_w_kernel<<<dim3(32, 32), dim3(32, 8), 0, stream>>>(Wk, WkT);
    transpose_w_kernel<<<dim3(32, 32), dim3(32, 8), 0, stream>>>(Wv, WvT);

    // pass 1: projections. Q scaled by 1/sqrt(1024); V computed transposed.
    gemm_nt<0><<<dim3(8, 64, 1), 256, 0, stream>>>(
        xb, 1024, 0, WqT, 1024, 0, Qs, 1024, 0, 1024, 0.03125f, nullptr);
    gemm_nt<0><<<dim3(8, 64, 1), 256, 0, stream>>>(
        xb, 1024, 0, WkT, 1024, 0, Kb, 1024, 0, 1024, 1.0f, nullptr);
    gemm_nt<0><<<dim3(64, 8, 1), 256, 0, stream>>>(
        WvT, 1024, 0, xb, 1024, 0, Vt, 8192, 0, 1024, 1.0f, nullptr);

    // pass 2: S = Qs*K^T per batch, causal mask, P = exp(S) bf16, row sums -> l
    gemm_nt<2><<<dim3(16, 16, 4), 256, 0, stream>>>(
        Qs, 1024, 2048LL * 1024, Kb, 1024, 2048LL * 1024,
        P, 2048, 2048LL * 2048 * 2, 1024, 1.0f, l);

    // pass 3: O = (P/l) * V  (K limited per row-tile to the causal extent)
    gemm_nt<3><<<dim3(8, 16, 4), 256, 0, stream>>>(
        P, 2048, 2048LL * 2048, Vt + 0, 8192, 2048LL,
        out, 1024, 2048LL * 1024 * 4, 0, 1.0f, l);
}

// Round 2
// 303.430 us; speedup vs baseline: 1.0252x; 1.0252x over previous
//
#include <hip/hip_runtime.h>
#include <cstdint>
#include <cstddef>

typedef unsigned short u16;
typedef __bf16 bf16x8 __attribute__((ext_vector_type(8)));
typedef float f32x4 __attribute__((ext_vector_type(4)));

// fp32 -> bf16 round-to-nearest-even (inputs finite)
__device__ inline u16 f2b(float f) {
    uint32_t u = __builtin_bit_cast(uint32_t, f);
    u += 0x7FFFu + ((u >> 16) & 1u);
    return (u16)(u >> 16);
}

// async global->LDS DMA, 16B per lane; lds dst must be wave-uniform base
__device__ inline void gl2lds16(const u16* g, u16* l) {
    __builtin_amdgcn_global_load_lds(
        (const __attribute__((address_space(1))) void*)g,
        (__attribute__((address_space(3))) void*)l, 16, 0, 0);
}

// ---------------- prep: fp32 -> bf16 convert (x) ----------------
__global__ void convert_x_kernel(const float* __restrict__ x, u16* __restrict__ xb) {
    size_t i = ((size_t)blockIdx.x * 256 + threadIdx.x) * 4;
    float4 v = *(const float4*)(x + i);
    uint2 pack;
    pack.x = (uint32_t)f2b(v.x) | ((uint32_t)f2b(v.y) << 16);
    pack.y = (uint32_t)f2b(v.z) | ((uint32_t)f2b(v.w) << 16);
    *(uint2*)(xb + i) = pack;
}

// ---------------- prep: W [k][n] fp32 -> WT [n][k] bf16, scaled ----------------
__global__ void transpose_w_kernel(const float* __restrict__ W, u16* __restrict__ WT,
                                   float scale) {
    __shared__ u16 t[32][33];
    const int bx = blockIdx.x * 32;  // n origin
    const int by = blockIdx.y * 32;  // k origin
    const int tx = threadIdx.x, ty = threadIdx.y;
    #pragma unroll
    for (int r = 0; r < 32; r += 8)
        t[ty + r][tx] = f2b(W[(size_t)(by + ty + r) * 1024 + bx + tx] * scale);
    __syncthreads();
    #pragma unroll
    for (int r = 0; r < 32; r += 8)
        WT[(size_t)(bx + ty + r) * 1024 + (by + tx)] = t[tx][ty + r];
}

// ---------------- generic NT GEMM: C = A (MxK) * B^T, B stored [N][K] ----------------
// m97 structure: global_load_lds(16B) staging -> barrier -> ds_read_b128 + MFMA -> barrier
// EPI 0: C bf16 = acc*scale
// EPI 2: causal mask + exp -> P bf16, atomicAdd row sums into lbuf
// EPI 3: C fp32 = acc / lbuf[row], K limited to (it+1)*128
template<int EPI>
__global__ __launch_bounds__(256)
void gemm_nt(const u16* __restrict__ A, int lda, long long sAz,
             const u16* __restrict__ B, int ldb, long long sBz,
             void* __restrict__ Cv, int ldc, long long sCzBytes,
             int K, float scale, float* __restrict__ lbuf) {
    constexpr int BM = 128, BN = 128, BK = 32;
    __shared__ __align__(16) u16 Asm[BM * BK];   // 8 KB, NO padding (global_load_lds)
    __shared__ __align__(16) u16 Bsm[BN * BK];   // 8 KB

    const int jt = blockIdx.x, it = blockIdx.y, z = blockIdx.z;
    if (EPI == 2) { if (jt > it) return; }  // causal tile skip (block-uniform)

    A += (size_t)z * sAz;
    B += (size_t)z * sBz;
    char* Cb = (char*)Cv + (size_t)z * sCzBytes;
    if (EPI == 2 || EPI == 3) lbuf += (size_t)z * 2048;

    const int m0 = it * BM, n0 = jt * BN;
    const int Kloc = (EPI == 3) ? (it + 1) * 128 : K;

    const int tid = threadIdx.x;
    const int lane = tid & 63, wave = tid >> 6;
    const int wm = wave >> 1, wn = wave & 1;       // 2x2 wave grid, 64x64 per wave
    const int fl = lane & 15, fh = lane >> 4;

    // staging: wave handles two 16-row chunks of A and of B.
    // instruction q covers rows q*16..q*16+16; lane l -> row q*16 + (l>>2), k-off (l&3)*8
    const int q0 = wave * 2;
    const int lrow = lane >> 2, lkoff = (lane & 3) * 8;
    const u16* ApL0 = A + (size_t)(m0 + q0 * 16 + lrow) * lda + lkoff;
    const u16* ApL1 = ApL0 + (size_t)16 * lda;
    const u16* BpL0 = B + (size_t)(n0 + q0 * 16 + lrow) * ldb + lkoff;
    const u16* BpL1 = BpL0 + (size_t)16 * ldb;
    u16* AsD0 = &Asm[q0 * 512];
    u16* AsD1 = &Asm[q0 * 512 + 512];
    u16* BsD0 = &Bsm[q0 * 512];
    u16* BsD1 = &Bsm[q0 * 512 + 512];

    const f32x4 vzero = {0.f, 0.f, 0.f, 0.f};
    f32x4 acc[4][4];
    #pragma unroll
    for (int i = 0; i < 4; ++i)
        #pragma unroll
        for (int j = 0; j < 4; ++j) acc[i][j] = vzero;

    for (int k0 = 0; k0 < Kloc; k0 += BK) {
        gl2lds16(ApL0 + k0, AsD0);
        gl2lds16(ApL1 + k0, AsD1);
        gl2lds16(BpL0 + k0, BsD0);
        gl2lds16(BpL1 + k0, BsD1);
        __syncthreads();   // drains vmcnt (DMA done) for all waves
        bf16x8 af[4], bfr[4];
        #pragma unroll
        for (int t = 0; t < 4; ++t) {
            af[t]  = *(const bf16x8*)&Asm[(wm * 64 + t * 16 + fl) * BK + fh * 8];
            bfr[t] = *(const bf16x8*)&Bsm[(wn * 64 + t * 16 + fl) * BK + fh * 8];
        }
        #pragma unroll
        for (int mt = 0; mt < 4; ++mt)
            #pragma unroll
            for (int nt = 0; nt < 4; ++nt)
                acc[mt][nt] = __builtin_amdgcn_mfma_f32_16x16x32_bf16(
                    af[mt], bfr[nt], acc[mt][nt], 0, 0, 0);
        __syncthreads();   // protect LDS from next iteration's DMA
    }

    if (EPI == 0) {
        u16* Cp = (u16*)Cb;
        #pragma unroll
        for (int mt = 0; mt < 4; ++mt)
            #pragma unroll
            for (int nt = 0; nt < 4; ++nt)
                #pragma unroll
                for (int r = 0; r < 4; ++r) {
                    int row = m0 + wm * 64 + mt * 16 + fh * 4 + r;
                    int col = n0 + wn * 64 + nt * 16 + fl;
                    Cp[(size_t)row * ldc + col] = f2b(acc[mt][nt][r] * scale);
                }
    } else if (EPI == 2) {
        u16* Cp = (u16*)Cb;
        #pragma unroll
        for (int mt = 0; mt < 4; ++mt)
            #pragma unroll
            for (int r = 0; r < 4; ++r) {
                int row = m0 + wm * 64 + mt * 16 + fh * 4 + r;
                float part = 0.f;
                #pragma unroll
                for (int nt = 0; nt < 4; ++nt) {
                    int col = n0 + wn * 64 + nt * 16 + fl;
                    float p = (col <= row) ? __expf(acc[mt][nt][r]) : 0.f;
                    part += p;
                    Cp[(size_t)row * ldc + col] = f2b(p);
                }
                #pragma unroll
                for (int off = 1; off < 16; off <<= 1)
                    part += __shfl_xor(part, off, 64);
                if (fl == 0) atomicAdd(lbuf + row, part);
            }
    } else {
        float* Cp = (float*)Cb;
        #pragma unroll
        for (int mt = 0; mt < 4; ++mt)
            #pragma unroll
            for (int r = 0; r < 4; ++r) {
                int row = m0 + wm * 64 + mt * 16 + fh * 4 + r;
                float inv = 1.0f / lbuf[row];
                #pragma unroll
                for (int nt = 0; nt < 4; ++nt) {
                    int col = n0 + wn * 64 + nt * 16 + fl;
                    Cp[(size_t)row * ldc + col] = acc[mt][nt][r] * inv;
                }
            }
    }
}

extern "C" void kernel_launch(void* const* d_in, const int* in_sizes, int n_in,
                              void* d_out, int out_size, void* d_ws, size_t ws_size,
                              hipStream_t stream) {
    (void)in_sizes; (void)n_in; (void)out_size; (void)ws_size;
    const float* x  = (const float*)d_in[0];
    const float* Wq = (const float*)d_in[1];
    const float* Wk = (const float*)d_in[2];
    const float* Wv = (const float*)d_in[3];
    float* out = (float*)d_out;

    const size_t MB = 1u << 20;
    char* ws = (char*)d_ws;
    u16* xb   = (u16*)(ws);              // [8192][1024] bf16       16 MB
    u16* QKWT = (u16*)(ws + 16 * MB);    // [2048][1024] bf16 (WqT scaled | WkT)  4 MB
    u16* WvT  = (u16*)(ws + 20 * MB);    // [1024][1024] bf16        2 MB
    u16* QK   = (u16*)(ws + 22 * MB);    // [8192][2048] bf16 (Q|K) 32 MB
    u16* Vt   = (u16*)(ws + 54 * MB);    // V^T [1024][8192]        16 MB
    u16* P    = (u16*)(ws + 70 * MB);    // exp(S) [4][2048][2048]  32 MB
    float* l  = (float*)(ws + 102 * MB); // row sums [4][2048]      32 KB

    // prep
    hipMemsetAsync(l, 0, 8192 * sizeof(float), stream);
    convert_x_kernel<<<8192, 256, 0, stream>>>(x, xb);
    // Wq transposed with 1/sqrt(1024) folded in; Wk plain; stacked [2048][1024]
    transpose_w_kernel<<<dim3(32, 32), dim3(32, 8), 0, stream>>>(Wq, QKWT, 0.03125f);
    transpose_w_kernel<<<dim3(32, 32), dim3(32, 8), 0, stream>>>(Wk, QKWT + 1024 * 1024, 1.0f);
    transpose_w_kernel<<<dim3(32, 32), dim3(32, 8), 0, stream>>>(Wv, WvT, 1.0f);

    // pass 1a: fused Q|K projection -> QK [8192][2048]
    gemm_nt<0><<<dim3(16, 64, 1), 256, 0, stream>>>(
        xb, 1024, 0, QKWT, 1024, 0, QK, 2048, 0, 1024, 1.0f, nullptr);
    // pass 1b: V^T = WvT * xb^T -> [1024][8192]
    gemm_nt<0><<<dim3(64, 8, 1), 256, 0, stream>>>(
        WvT, 1024, 0, xb, 1024, 0, Vt, 8192, 0, 1024, 1.0f, nullptr);

    // pass 2: S = Q*K^T per batch (Q,K interleaved in QK, row stride 2048),
    // causal mask, P = exp(S) bf16, row sums -> l
    gemm_nt<2><<<dim3(16, 16, 4), 256, 0, stream>>>(
        QK, 2048, 2048LL * 2048, QK + 1024, 2048, 2048LL * 2048,
        P, 2048, 2048LL * 2048 * 2, 1024, 1.0f, l);

    // pass 3: O = (P/l) * V  (K limited per row-tile to the causal extent)
    gemm_nt<3><<<dim3(8, 16, 4), 256, 0, stream>>>(
        P, 2048, 2048LL * 2048, Vt, 8192, 2048LL,
        out, 1024, 2048LL * 1024 * 4, 0, 1.0f, l);
}

// Round 3
// 257.609 us; speedup vs baseline: 1.2075x; 1.1779x over previous
//
#include <hip/hip_runtime.h>
#include <cstdint>
#include <cstddef>

typedef unsigned short u16;
typedef __bf16 bf16x8 __attribute__((ext_vector_type(8)));
typedef float f32x4 __attribute__((ext_vector_type(4)));

// fp32 -> bf16 round-to-nearest-even (inputs finite)
__device__ inline u16 f2b(float f) {
    uint32_t u = __builtin_bit_cast(uint32_t, f);
    u += 0x7FFFu + ((u >> 16) & 1u);
    return (u16)(u >> 16);
}

// async global->LDS DMA, 16B per lane; lds dst is wave-uniform base + lane*16
__device__ inline void gl2lds16(const u16* g, u16* l) {
    __builtin_amdgcn_global_load_lds(
        (const __attribute__((address_space(1))) void*)g,
        (__attribute__((address_space(3))) void*)l, 16, 0, 0);
}

// ---------------- prep: fp32 -> bf16 convert (x) ----------------
__global__ void convert_x_kernel(const float* __restrict__ x, u16* __restrict__ xb) {
    size_t i = ((size_t)blockIdx.x * 256 + threadIdx.x) * 4;
    float4 v = *(const float4*)(x + i);
    uint2 pack;
    pack.x = (uint32_t)f2b(v.x) | ((uint32_t)f2b(v.y) << 16);
    pack.y = (uint32_t)f2b(v.z) | ((uint32_t)f2b(v.w) << 16);
    *(uint2*)(xb + i) = pack;
}

// ---------------- prep: all 3 weights [k][n] fp32 -> [n][k] bf16, z-fused ----
__global__ void transpose_w_kernel(const float* __restrict__ Wq,
                                   const float* __restrict__ Wk,
                                   const float* __restrict__ Wv,
                                   u16* __restrict__ QKWT, u16* __restrict__ WvT) {
    __shared__ u16 t[32][33];
    const int z = blockIdx.z;
    const float* W = (z == 0) ? Wq : ((z == 1) ? Wk : Wv);
    u16* dst = (z == 0) ? QKWT : ((z == 1) ? QKWT + 1024 * 1024 : WvT);
    const float scale = (z == 0) ? 0.03125f : 1.0f;  // fold 1/sqrt(1024) into Wq
    const int bx = blockIdx.x * 32;  // n origin
    const int by = blockIdx.y * 32;  // k origin
    const int tx = threadIdx.x, ty = threadIdx.y;
    #pragma unroll
    for (int r = 0; r < 32; r += 8)
        t[ty + r][tx] = f2b(W[(size_t)(by + ty + r) * 1024 + bx + tx] * scale);
    __syncthreads();
    #pragma unroll
    for (int r = 0; r < 32; r += 8)
        dst[(size_t)(bx + ty + r) * 1024 + (by + tx)] = t[tx][ty + r];
}

// ---------------- NT GEMM body: C = A (MxK) * B^T, B stored [N][K] -----------
// Software-pipelined: dbuf LDS, 1 barrier/iter, DMA(k+1) issued before MFMA(k).
// EPI 0: C bf16 = acc
// EPI 2: causal mask + exp -> P bf16, atomicAdd row sums into lrow
// EPI 3: C fp32 = acc / lrow[row]
template<int EPI>
__device__ __forceinline__ void gemm_body(
    u16* __restrict__ smem,   // 16384 u16 = 32 KB: A0 | A1 | B0 | B1 (4096 each)
    const u16* __restrict__ A, int lda,
    const u16* __restrict__ B, int ldb,
    char* __restrict__ Cb, int ldc,
    int m0, int n0, int Kloc, float* __restrict__ lrow) {
    constexpr int BK = 32;
    const int tid = threadIdx.x;
    const int lane = tid & 63, wave = tid >> 6;
    const int wm = wave >> 1, wn = wave & 1;       // 2x2 wave grid, 64x64 per wave
    const int fl = lane & 15, fh = lane >> 4;

    // staging: wave covers two 16-row chunks of A and of B per instruction set
    const int q0 = wave * 2;
    const int srow = lane >> 2, skoff = (lane & 3) * 8;
    const u16* ApL0 = A + (size_t)(m0 + q0 * 16 + srow) * lda + skoff;
    const u16* ApL1 = ApL0 + (size_t)16 * lda;
    const u16* BpL0 = B + (size_t)(n0 + q0 * 16 + srow) * ldb + skoff;
    const u16* BpL1 = BpL0 + (size_t)16 * ldb;

    u16* const Ab[2] = { smem, smem + 4096 };
    u16* const Bb[2] = { smem + 8192, smem + 12288 };

    auto issue = [&](int buf, int k0) {
        gl2lds16(ApL0 + k0, Ab[buf] + q0 * 512);
        gl2lds16(ApL1 + k0, Ab[buf] + q0 * 512 + 512);
        gl2lds16(BpL0 + k0, Bb[buf] + q0 * 512);
        gl2lds16(BpL1 + k0, Bb[buf] + q0 * 512 + 512);
    };

    const f32x4 vzero = {0.f, 0.f, 0.f, 0.f};
    f32x4 acc[4][4];
    #pragma unroll
    for (int i = 0; i < 4; ++i)
        #pragma unroll
        for (int j = 0; j < 4; ++j) acc[i][j] = vzero;

    issue(0, 0);
    int buf = 0;
    for (int k0 = 0; k0 < Kloc; k0 += BK, buf ^= 1) {
        __syncthreads();                       // publishes `buf` (drains its DMA)
        if (k0 + BK < Kloc) issue(buf ^ 1, k0 + BK);   // prefetch next tile
        bf16x8 af[4], bfr[4];
        #pragma unroll
        for (int t = 0; t < 4; ++t) {
            af[t]  = *(const bf16x8*)&Ab[buf][(wm * 64 + t * 16 + fl) * BK + fh * 8];
            bfr[t] = *(const bf16x8*)&Bb[buf][(wn * 64 + t * 16 + fl) * BK + fh * 8];
        }
        #pragma unroll
        for (int mt = 0; mt < 4; ++mt)
            #pragma unroll
            for (int nt = 0; nt < 4; ++nt)
                acc[mt][nt] = __builtin_amdgcn_mfma_f32_16x16x32_bf16(
                    af[mt], bfr[nt], acc[mt][nt], 0, 0, 0);
    }

    if (EPI == 0) {
        u16* Cp = (u16*)Cb;
        #pragma unroll
        for (int mt = 0; mt < 4; ++mt)
            #pragma unroll
            for (int nt = 0; nt < 4; ++nt)
                #pragma unroll
                for (int r = 0; r < 4; ++r) {
                    int row = m0 + wm * 64 + mt * 16 + fh * 4 + r;
                    int col = n0 + wn * 64 + nt * 16 + fl;
                    Cp[(size_t)row * ldc + col] = f2b(acc[mt][nt][r]);
                }
    } else if (EPI == 2) {
        u16* Cp = (u16*)Cb;
        #pragma unroll
        for (int mt = 0; mt < 4; ++mt)
            #pragma unroll
            for (int r = 0; r < 4; ++r) {
                int row = m0 + wm * 64 + mt * 16 + fh * 4 + r;
                float part = 0.f;
                #pragma unroll
                for (int nt = 0; nt < 4; ++nt) {
                    int col = n0 + wn * 64 + nt * 16 + fl;
                    float p = (col <= row) ? __expf(acc[mt][nt][r]) : 0.f;
                    part += p;
                    Cp[(size_t)row * ldc + col] = f2b(p);
                }
                #pragma unroll
                for (int off = 1; off < 16; off <<= 1)
                    part += __shfl_xor(part, off, 64);
                if (fl == 0) atomicAdd(lrow + row, part);
            }
    } else {
        float* Cp = (float*)Cb;
        #pragma unroll
        for (int mt = 0; mt < 4; ++mt)
            #pragma unroll
            for (int r = 0; r < 4; ++r) {
                int row = m0 + wm * 64 + mt * 16 + fh * 4 + r;
                float inv = 1.0f / lrow[row];
                #pragma unroll
                for (int nt = 0; nt < 4; ++nt) {
                    int col = n0 + wn * 64 + nt * 16 + fl;
                    Cp[(size_t)row * ldc + col] = acc[mt][nt][r] * inv;
                }
            }
    }
}

// ---- merged projection dispatch: QK (1024 blocks) + V^T (512 blocks) --------
__global__ __launch_bounds__(256)
void proj_kernel(const u16* __restrict__ xb, const u16* __restrict__ QKWT,
                 const u16* __restrict__ WvT, u16* __restrict__ QK,
                 u16* __restrict__ Vt) {
    __shared__ __align__(16) u16 smem[16384];
    int bid = blockIdx.x;
    const u16 *A, *B;
    char* C;
    int lda, ldb, ldc, m0, n0;
    if (bid < 1024) {            // QK: [8192][2048] = xb @ QKWT^T
        int jt = bid & 15, it = bid >> 4;
        A = xb;  lda = 1024;  B = QKWT;  ldb = 1024;
        C = (char*)QK;  ldc = 2048;  m0 = it * 128;  n0 = jt * 128;
    } else {                     // V^T: [1024][8192] = WvT @ xb^T
        int b = bid - 1024;
        int jt = b & 63, it = b >> 6;
        A = WvT;  lda = 1024;  B = xb;  ldb = 1024;
        C = (char*)Vt;  ldc = 8192;  m0 = it * 128;  n0 = jt * 128;
    }
    gemm_body<0>(smem, A, lda, B, ldb, C, ldc, m0, n0, 1024, nullptr);
}

// ---- scores: compact triangular grid, P = exp(masked QK^T), row sums --------
__global__ __launch_bounds__(256)
void scores_kernel(const u16* __restrict__ QK, u16* __restrict__ P,
                   float* __restrict__ l) {
    __shared__ __align__(16) u16 smem[16384];
    const int t = blockIdx.x, z = blockIdx.y;
    int it = (int)((sqrtf(8.0f * t + 1.0f) - 1.0f) * 0.5f);
    while ((it + 1) * (it + 2) / 2 <= t) ++it;
    while (it * (it + 1) / 2 > t) --it;
    const int jt = t - it * (it + 1) / 2;
    const u16* Qz = QK + (size_t)z * 2048 * 2048;  // Q cols [0,1024)
    const u16* Kz = Qz + 1024;                     // K cols [1024,2048)
    u16* Pz = P + (size_t)z * 2048 * 2048;
    gemm_body<2>(smem, Qz, 2048, Kz, 2048, (char*)Pz, 2048,
                 it * 128, jt * 128, 1024, l + (size_t)z * 2048);
}

// ---- output: O = (P/l) @ V, causal K-extent, heavy row-tiles first ----------
__global__ __launch_bounds__(256)
void out_kernel(const u16* __restrict__ P, const u16* __restrict__ Vt,
                float* __restrict__ out, float* __restrict__ l) {
    __shared__ __align__(16) u16 smem[16384];
    const int jt = blockIdx.x;
    const int it = 15 - (int)blockIdx.y;   // heavy first (Kloc = (it+1)*128)
    const int z = blockIdx.z;
    gemm_body<3>(smem, P + (size_t)z * 2048 * 2048, 2048,
                 Vt + (size_t)z * 2048, 8192,
                 (char*)(out + (size_t)z * 2048 * 1024), 1024,
                 it * 128, jt * 128, (it + 1) * 128, l + (size_t)z * 2048);
}

extern "C" void kernel_launch(void* const* d_in, const int* in_sizes, int n_in,
                              void* d_out, int out_size, void* d_ws, size_t ws_size,
                              hipStream_t stream) {
    (void)in_sizes; (void)n_in; (void)out_size; (void)ws_size;
    const float* x  = (const float*)d_in[0];
    const float* Wq = (const float*)d_in[1];
    const float* Wk = (const float*)d_in[2];
    const float* Wv = (const float*)d_in[3];
    float* out = (float*)d_out;

    const size_t MB = 1u << 20;
    char* ws = (char*)d_ws;
    u16* xb   = (u16*)(ws);              // [8192][1024] bf16       16 MB
    u16* QKWT = (u16*)(ws + 16 * MB);    // [2048][1024] (WqT*s | WkT) 4 MB
    u16* WvT  = (u16*)(ws + 20 * MB);    // [1024][1024]             2 MB
    u16* QK   = (u16*)(ws + 22 * MB);    // [8192][2048] (Q|K)      32 MB
    u16* Vt   = (u16*)(ws + 54 * MB);    // V^T [1024][8192]        16 MB
    u16* P    = (u16*)(ws + 70 * MB);    // exp(S) [4][2048][2048]  32 MB
    float* l  = (float*)(ws + 102 * MB); // row sums [4][2048]      32 KB

    hipMemsetAsync(l, 0, 8192 * sizeof(float), stream);
    convert_x_kernel<<<8192, 256, 0, stream>>>(x, xb);
    transpose_w_kernel<<<dim3(32, 32, 3), dim3(32, 8), 0, stream>>>(Wq, Wk, Wv, QKWT, WvT);

    proj_kernel<<<1536, 256, 0, stream>>>(xb, QKWT, WvT, QK, Vt);
    scores_kernel<<<dim3(136, 4), 256, 0, stream>>>(QK, P, l);
    out_kernel<<<dim3(8, 16, 4), 256, 0, stream>>>(P, Vt, out, l);
}